// Round 3
// baseline (7796.221 us; speedup 1.0000x reference)
//
#include <hip/hip_runtime.h>
#include <math.h>

// QuantumMambaSSMCore R3: single-wave, zero-barrier state-vector scan.
//  - 1 wave (64 thr) per block, 128 blocks, 16 amps/thread.
//  - Layout: phys bits {0,1,5,6}->reg (r0..r3), {2,3,4,7,8,9}->lane (L0..L5).
//  - NO __syncthreads inside the t-loop: shfl_xor gates, butterfly measurement,
//    per-lane redundant h/sincos, fire-and-forget stores, uniform s_load tables.
//  - CNOTs folded into GF(2) masks; 40 QSVT RZs fused into one per-amp phase;
//    RX*RY*RZ fused into 20 constant SU(2) gates (stored in 640B LDS).

#define PIF 3.14159265358979323846f

constexpr int NQ = 10, SEQ = 512, NB = 128, NTHR = 64, RECF = 72;

struct CTbl { int vu[2][NQ], mu[2][NQ], mz[4][NQ], vf[NQ], mf[NQ], zm[NQ]; };

constexpr CTbl build_tbl() {
  CTbl t{};
  unsigned mrow[NQ], vcol[NQ];
  for (int b = 0; b < NQ; ++b) { mrow[b] = 1u << b; vcol[b] = 1u << b; }
  for (int d = 0; d < 4; ++d) {
    for (int i = 0; i < NQ; ++i) t.mz[d][i] = (int)mrow[9 - i];
    for (int i = 0; i < NQ - 1; ++i) {           // CNOT(i, i+1)
      int bc = 9 - i, bt = 8 - i;
      mrow[bt] ^= mrow[bc];
      vcol[bc] ^= vcol[bt];
    }
    { int bc = 0, bt = 9;                        // CNOT(9, 0)
      mrow[bt] ^= mrow[bc];
      vcol[bc] ^= vcol[bt]; }
  }
  for (int l = 0; l < 2; ++l) {
    for (int i = 0; i < NQ; ++i) { t.vu[l][i] = (int)vcol[9 - i]; t.mu[l][i] = (int)mrow[9 - i]; }
    for (int i = 0; i < NQ - 1; ++i) {
      int bc = 9 - i, bt = 8 - i;
      mrow[bt] ^= mrow[bc];
      vcol[bc] ^= vcol[bt];
    }
  }
  for (int i = 0; i < NQ; ++i) { t.vf[i] = (int)vcol[9 - i]; t.mf[i] = (int)mrow[9 - i]; }
  for (int i = 0; i < NQ; ++i) t.zm[i] = (int)mrow[9 - i];
  return t;
}
constexpr CTbl CT = build_tbl();

// phys-bit -> storage decomposition
constexpr int regPart(int x)  { return ((x >> 0) & 1) | (((x >> 1) & 1) << 1) |
                                       (((x >> 5) & 1) << 2) | (((x >> 6) & 1) << 3); }
constexpr int lanePart(int x) { return ((x >> 2) & 1) | (((x >> 3) & 1) << 1) | (((x >> 4) & 1) << 2) |
                                       (((x >> 7) & 1) << 3) | (((x >> 8) & 1) << 4) | (((x >> 9) & 1) << 5); }

typedef __attribute__((ext_vector_type(2))) float v2;

// ---------- precompute kernel: h-independent per-step tables ----------
__global__ __launch_bounds__(256) void qmamba_pre(
    const float* __restrict__ angles, const float* __restrict__ Wx,
    const float* __restrict__ Wdt, const float* __restrict__ bdt,
    const float* __restrict__ pc, float* __restrict__ tbl)
{
  int idx = blockIdx.x * 256 + threadIdx.x;        // (b*SEQ + t)
  if (idx >= NB * SEQ) return;
  const float* ar = angles + (size_t)idx * NQ;
  float a[NQ];
#pragma unroll
  for (int n = 0; n < NQ; ++n) a[n] = ar[n];
  float dtr[5];
#pragma unroll
  for (int r = 0; r < 5; ++r) {
    float acc = 0.f;
#pragma unroll
    for (int n = 0; n < NQ; ++n) acc += a[n] * Wx[r * NQ + n];
    dtr[r] = acc;
  }
  float pcr[4] = {pc[0], pc[1], pc[2], pc[3]};
  float* rec = tbl + (size_t)idx * RECF;
#pragma unroll
  for (int w = 0; w < NQ; ++w) {
    float lin = bdt[w];
#pragma unroll
    for (int r = 0; r < 5; ++r) lin += dtr[r] * Wdt[w * 5 + r];
    float sp = lin > 0.f ? lin + log1pf(__expf(-lin)) : log1pf(__expf(lin));
    float th = tanhf(sp) * PIF;                    // dt_angles
#pragma unroll
    for (int d = 0; d < 4; ++d) rec[d * 10 + w] = 0.5f * pcr[d] * th * PIF;
    float fa = 0.5f * a[w] * th;
    rec[40 + w] = __cosf(fa);
    rec[50 + w] = __sinf(fa);
    float Cv = 0.f;
#pragma unroll
    for (int n = 0; n < NQ; ++n) Cv += a[n] * Wx[(15 + w) * NQ + n];
    rec[60 + w] = Cv;
  }
}

// ---------- main scan kernel: one wave per batch element ----------
__global__ __launch_bounds__(NTHR, 1) void qmamba_main(
    const float* __restrict__ angles, const float* __restrict__ Wx,
    const float* __restrict__ Wdt, const float* __restrict__ bdt,
    const float* __restrict__ pc, const float* __restrict__ cp,
    const float* __restrict__ Dg, const float* __restrict__ tbl,
    float* __restrict__ out)
{
  __shared__ float4 uuL[20][2];    // fused U: [0]={u00,u01}, [1]={u10,u11}

  const int lane = threadIdx.x;    // 0..63 (single wave)
  const int b    = blockIdx.x;

  // fused variational unitaries U = RZ(g)*RY(be)*RX(al), once per launch
  if (lane < 20) {
    int k = lane * 3;
    float al = 0.5f * cp[k], be = 0.5f * cp[k + 1], ga = 0.5f * cp[k + 2];
    float ca = __cosf(al), sa = __sinf(al);
    float cb = __cosf(be), sb = __sinf(be);
    float cg = __cosf(ga), sg = __sinf(ga);
    float2 M00 = make_float2(cb * ca,  sb * sa);
    float2 M01 = make_float2(-sb * ca, -cb * sa);
    float2 M10 = make_float2(sb * ca,  -cb * sa);
    float2 M11 = make_float2(cb * ca,  -sb * sa);
    float2 e0 = make_float2(cg, -sg), e1 = make_float2(cg, sg);
    auto cm = [](float2 a, float2 c) {
      return make_float2(a.x * c.x - a.y * c.y, a.x * c.y + a.y * c.x);
    };
    float2 u00 = cm(M00, e0), u01 = cm(M01, e0), u10 = cm(M10, e1), u11 = cm(M11, e1);
    uuL[lane][0] = make_float4(u00.x, u00.y, u01.x, u01.y);
    uuL[lane][1] = make_float4(u10.x, u10.y, u11.x, u11.y);
  }
  __syncthreads();   // once per launch (single wave: just a waitcnt)

  const float Dv  = (lane < NQ) ? Dg[lane] : 0.f;
  float pcr[4];
#pragma unroll
  for (int d = 0; d < 4; ++d) pcr[d] = pc[d];

  // hoisted per-lane parity word for the 40 fused-RZ masks (bit = flip-sign)
  unsigned PW0 = 0, PW1 = 0;
#pragma unroll
  for (int k = 0; k < 40; ++k) {
    const int lm = lanePart(CT.mz[k / 10][k % 10]);
    unsigned flip = (__popc(lane & lm) & 1) ^ 1;   // contribution +th iff lane-parity odd
    if (k < 32) PW0 |= flip << k; else PW1 |= flip << (k - 32);
  }

  // per-wire cos/sin of h/2 (h0 = 0)
  float hc[NQ], hs[NQ];
#pragma unroll
  for (int w = 0; w < NQ; ++w) { hc[w] = 1.f; hs[w] = 0.f; }

  v2 amp[16];

#pragma unroll 1
  for (int t = 0; t < SEQ; ++t) {
    const float* arow = angles + (size_t)(b * SEQ + t) * NQ;
    float thv[40], fcv[10], fsv[10], Cv, av;

    if (tbl) {
      const float* rec = tbl + (size_t)(b * SEQ + t) * RECF;   // uniform -> s_load
#pragma unroll
      for (int k = 0; k < 40; ++k) thv[k] = rec[k];
#pragma unroll
      for (int i = 0; i < NQ; ++i) { fcv[i] = rec[40 + i]; fsv[i] = rec[50 + i]; }
      Cv = (lane < NQ) ? rec[60 + lane] : 0.f;
      av = (lane < NQ) ? arow[lane] : 0.f;
    } else {
      // fallback: every lane computes the whole per-step preamble redundantly
      float a[NQ];
#pragma unroll
      for (int n = 0; n < NQ; ++n) a[n] = arow[n];
      float dtr[5];
#pragma unroll
      for (int r = 0; r < 5; ++r) {
        float acc = 0.f;
#pragma unroll
        for (int n = 0; n < NQ; ++n) acc += a[n] * Wx[r * NQ + n];
        dtr[r] = acc;
      }
#pragma unroll
      for (int w = 0; w < NQ; ++w) {
        float lin = bdt[w];
#pragma unroll
        for (int r = 0; r < 5; ++r) lin += dtr[r] * Wdt[w * 5 + r];
        float sp = lin > 0.f ? lin + log1pf(__expf(-lin)) : log1pf(__expf(lin));
        float th = tanhf(sp) * PIF;
#pragma unroll
        for (int d = 0; d < 4; ++d) thv[d * 10 + w] = 0.5f * pcr[d] * th * PIF;
        float fa = 0.5f * a[w] * th;
        fcv[w] = __cosf(fa);
        fsv[w] = __sinf(fa);
      }
      float Cacc = 0.f;
      int w10 = lane < NQ ? lane : 0;
#pragma unroll
      for (int n = 0; n < NQ; ++n) Cacc += a[n] * Wx[(15 + w10) * NQ + n];
      Cv = (lane < NQ) ? Cacc : 0.f;
      av = (lane < NQ) ? a[w10] : 0.f;
    }

    // ---- Phase A: real product state from RY(h)|0>
    // lane bits (L,wire): (0,7)(1,6)(2,5)(3,2)(4,1)(5,0); reg bits (r,wire): (0,9)(1,8)(2,4)(3,3)
    float F;
    {
      F  = (lane & 1)  ? hs[7] : hc[7];
      F *= (lane & 2)  ? hs[6] : hc[6];
      F *= (lane & 4)  ? hs[5] : hc[5];
      F *= (lane & 8)  ? hs[2] : hc[2];
      F *= (lane & 16) ? hs[1] : hc[1];
      F *= (lane & 32) ? hs[0] : hc[0];
    }
    float g01[4], G[16];
    g01[0] = hc[9] * hc[8]; g01[1] = hs[9] * hc[8];
    g01[2] = hc[9] * hs[8]; g01[3] = hs[9] * hs[8];
#pragma unroll
    for (int i = 0; i < 4; ++i) g01[i] *= F;
    {
      float g23[4];
      g23[0] = hc[4] * hc[3]; g23[1] = hs[4] * hc[3];
      g23[2] = hc[4] * hs[3]; g23[3] = hs[4] * hs[3];
#pragma unroll
      for (int r = 0; r < 16; ++r) G[r] = g01[r & 3] * g23[(r >> 2) & 3];
    }

    // ---- Phase B: fused 40-RZ phase per amp (buckets + 16-pt reg Walsh)
    float S[16];
#pragma unroll
    for (int g = 0; g < 16; ++g) S[g] = 0.f;
#pragma unroll
    for (int k = 0; k < 40; ++k) {
      const int m  = CT.mz[k / 10][k % 10];
      const int gr = regPart(m);
      unsigned fl = ((k < 32 ? (PW0 >> k) : (PW1 >> (k - 32))) & 1u) << 31;
      S[gr] += __int_as_float(__float_as_int(thv[k]) ^ fl);
    }
#pragma unroll
    for (int bb = 1; bb < 16; bb <<= 1) {
#pragma unroll
      for (int g = 0; g < 16; ++g)
        if (!(g & bb)) { float x = S[g], y = S[g | bb]; S[g] = x + y; S[g | bb] = x - y; }
    }
#pragma unroll
    for (int r = 0; r < 16; ++r) {
      float sn, cs;
      __sincosf(S[r], &sn, &cs);
      amp[r].x = G[r] * cs;
      amp[r].y = G[r] * sn;
    }

    // ---- pair-gate machinery (no barriers: shfl or register permute only)
    v2 p[16];
    auto fetch = [&](int v) {
      const int vl = lanePart(v), vr = regPart(v);
      if (vl == 0) {
#pragma unroll
        for (int r = 0; r < 16; ++r) p[r] = amp[r ^ vr];
      } else {
#pragma unroll
        for (int r = 0; r < 16; ++r) {
          v2 a0 = amp[r ^ vr];
          p[r].x = __shfl_xor(a0.x, vl, 64);
          p[r].y = __shfl_xor(a0.y, vl, 64);
        }
      }
    };

    auto gate_u = [&](int v, int m, int g) {
      fetch(v);
      float4 U0 = uuL[g][0], U1 = uuL[g][1];
      const bool plw = (__popc(lane & lanePart(m)) & 1) != 0;
      v2 u00 = {U0.x, U0.y}, u01 = {U0.z, U0.w}, u10 = {U1.x, U1.y}, u11 = {U1.z, U1.w};
      v2 A0 = plw ? u11 : u00, B0 = plw ? u10 : u01;
      v2 A1 = plw ? u00 : u11, B1 = plw ? u01 : u10;
      v2 A0n = {-A0.y, A0.y}, B0n = {-B0.y, B0.y};
      v2 A1n = {-A1.y, A1.y}, B1n = {-B1.y, B1.y};
      const int rm = regPart(m);
#pragma unroll
      for (int r = 0; r < 16; ++r) {
        const bool pr = (__popc(r & rm) & 1) != 0;
        v2 A = pr ? A1 : A0, An = pr ? A1n : A0n;
        v2 B = pr ? B1 : B0, Bn = pr ? B1n : B0n;
        v2 o = amp[r], q = p[r];
        v2 res = A.x * o;
        res += An * __builtin_shufflevector(o, o, 1, 0);
        res += B.x * q;
        res += Bn * __builtin_shufflevector(q, q, 1, 0);
        amp[r] = res;
      }
    };

    auto gate_ry = [&](int v, int m, float cc, float ss) {
      fetch(v);
      const bool plw = (__popc(lane & lanePart(m)) & 1) != 0;
      const float sgl = plw ? ss : -ss;
      const float msgl = -sgl;
      const int rm = regPart(m);
#pragma unroll
      for (int r = 0; r < 16; ++r) {
        const float co = (__popc(r & rm) & 1) ? msgl : sgl;
        amp[r] = cc * amp[r] + co * p[r];
      }
    };

    // ---- Phase C: 20 fused variational SU(2) gates
#pragma unroll
    for (int l = 0; l < 2; ++l) {
#pragma unroll
      for (int i = 0; i < NQ; ++i) gate_u(CT.vu[l][i], CT.mu[l][i], l * NQ + i);
    }
    // ---- Phase D: RY(x*dt)
#pragma unroll
    for (int i = 0; i < NQ; ++i) gate_ry(CT.vf[i], CT.mf[i], fcv[i], fsv[i]);

    // ---- measurement: z_w = sum_j |amp_j|^2 * (-1)^{popc(j & zm_w)}
    float q16[16];
#pragma unroll
    for (int r = 0; r < 16; ++r) q16[r] = amp[r].x * amp[r].x + amp[r].y * amp[r].y;

    float zt[NQ];
#pragma unroll
    for (int w = 0; w < NQ; ++w) {
      const int m  = CT.zm[w];
      const int rm = regPart(m), lm = lanePart(m);
      float acc = 0.f;
#pragma unroll
      for (int r = 0; r < 16; ++r) acc += (__popc(r & rm) & 1) ? -q16[r] : q16[r];
      if (__popc(lane & lm) & 1) acc = -acc;
#pragma unroll
      for (int k = 0; k < 6; ++k) acc += __shfl_xor(acc, 1 << k, 64);
      zt[w] = acc;              // every lane now holds z_w
    }

    // next-step h tables (computed redundantly per-lane; no communication)
#pragma unroll
    for (int w = 0; w < NQ; ++w) {
      float sn, cs;
      __sincosf(0.5f * zt[w], &sn, &cs);
      hc[w] = cs; hs[w] = sn;
    }

    // output: lane w stores row element w (fire-and-forget, never drained)
    float zsel = zt[0];
#pragma unroll
    for (int w = 1; w < NQ; ++w) zsel = (lane == w) ? zt[w] : zsel;
    if (lane < NQ) {
      out[(size_t)(b * SEQ + t) * NQ + lane] = Cv * zsel + Dv * av;
    }
  }
}

extern "C" void kernel_launch(void* const* d_in, const int* in_sizes, int n_in,
                              void* d_out, int out_size, void* d_ws, size_t ws_size,
                              hipStream_t stream) {
  (void)in_sizes; (void)n_in; (void)out_size;
  const float* angles = (const float*)d_in[0];
  const float* Wx     = (const float*)d_in[1];
  const float* Wdt    = (const float*)d_in[2];
  const float* bdt    = (const float*)d_in[3];
  const float* pc     = (const float*)d_in[4];
  const float* cp     = (const float*)d_in[5];
  const float* Dg     = (const float*)d_in[6];
  float* out = (float*)d_out;

  float* tbl = nullptr;
  const size_t need = (size_t)NB * SEQ * RECF * sizeof(float);
  if (ws_size >= need) {
    tbl = (float*)d_ws;
    hipLaunchKernelGGL(qmamba_pre, dim3((NB * SEQ + 255) / 256), dim3(256), 0, stream,
                       angles, Wx, Wdt, bdt, pc, tbl);
  }
  hipLaunchKernelGGL(qmamba_main, dim3(NB), dim3(NTHR), 0, stream,
                     angles, Wx, Wdt, bdt, pc, cp, Dg, tbl, out);
}

// Round 4
// 4999.300 us; speedup vs baseline: 1.5595x; 1.5595x over previous
//
#include <hip/hip_runtime.h>
#include <math.h>

// QuantumMambaSSMCore R4: single-wave, zero-barrier, zero-global-in-loop scan.
//  - 1 wave/block, 128 blocks, 16 amps/thread (v2 = complex).
//  - Storage map: regs r0..r3 = phys {2,4,6,8}; lanes L0..L5 = phys {0,5,1,7,3,9}.
//    Chosen so Phase-C gates split: 2 free / 10 DPP (VALU-only cross-lane) /
//    3 ds_swizzle / 5 ds_bpermute (constexpr-classified).
//  - Phase D (10 final RYs) fused into measurement: z_w = cos(th)*<Z_w> - sin(th)*<X_w>;
//    the 10 <X> fetches are independent -> pipelined, no serial gate chain.
//  - Per-step tables (52 floats) prefetched 1 step ahead into a float4 reg,
//    broadcast via v_readlane. Output buffered in LDS, stored after the loop.
//    NO global loads/stores and NO barriers inside the 512-step loop.

#define PIF 3.14159265358979323846f

constexpr int NQ = 10, SEQ = 512, NB = 128, NTHR = 64, RECF = 52;

struct CTbl { int vu[2][NQ], mu[2][NQ], mz[4][NQ], vf[NQ], zm[NQ]; };

constexpr CTbl build_tbl() {
  CTbl t{};
  unsigned mrow[NQ], vcol[NQ];
  for (int b = 0; b < NQ; ++b) { mrow[b] = 1u << b; vcol[b] = 1u << b; }
  for (int d = 0; d < 4; ++d) {
    for (int i = 0; i < NQ; ++i) t.mz[d][i] = (int)mrow[9 - i];
    for (int i = 0; i < NQ - 1; ++i) {           // CNOT(i, i+1)
      int bc = 9 - i, bt = 8 - i;
      mrow[bt] ^= mrow[bc];
      vcol[bc] ^= vcol[bt];
    }
    { int bc = 0, bt = 9;                        // CNOT(9, 0)
      mrow[bt] ^= mrow[bc];
      vcol[bc] ^= vcol[bt]; }
  }
  for (int l = 0; l < 2; ++l) {
    for (int i = 0; i < NQ; ++i) { t.vu[l][i] = (int)vcol[9 - i]; t.mu[l][i] = (int)mrow[9 - i]; }
    for (int i = 0; i < NQ - 1; ++i) {
      int bc = 9 - i, bt = 8 - i;
      mrow[bt] ^= mrow[bc];
      vcol[bc] ^= vcol[bt];
    }
  }
  for (int i = 0; i < NQ; ++i) t.vf[i] = (int)vcol[9 - i];
  for (int i = 0; i < NQ; ++i) t.zm[i] = (int)mrow[9 - i];
  return t;
}
constexpr CTbl CT = build_tbl();

// phys bit -> storage decomposition.  regs: p2,p4,p6,p8.  lanes: p0,p5,p1,p7,p3,p9.
constexpr int regPart(int x)  { return ((x >> 2) & 1) | (((x >> 4) & 1) << 1) |
                                       (((x >> 6) & 1) << 2) | (((x >> 8) & 1) << 3); }
constexpr int lanePart(int x) { return ((x >> 0) & 1) | (((x >> 5) & 1) << 1) |
                                       (((x >> 1) & 1) << 2) | (((x >> 7) & 1) << 3) |
                                       (((x >> 3) & 1) << 4) | (((x >> 9) & 1) << 5); }

typedef __attribute__((ext_vector_type(2))) float v2;

// ---------------- cross-lane exchange helpers ----------------
template<int C>
__device__ __forceinline__ int dpp1(int x) {
  return __builtin_amdgcn_update_dpp(x, x, C, 0xF, 0xF, false);
}
template<int VL>
__device__ __forceinline__ int lxi(int x) {   // DPP xor-exchange, 1 <= VL <= 15
  if constexpr (VL == 1)  return dpp1<0xB1>(x);
  else if constexpr (VL == 2)  return dpp1<0x4E>(x);
  else if constexpr (VL == 3)  return dpp1<0x1B>(x);
  else if constexpr (VL <= 7) {                 // VL = q ^ 7, q = (VL&3)^3
    constexpr int q = (VL & 3) ^ 3;
    int y = x;
    if constexpr (q == 1) y = dpp1<0xB1>(y);
    else if constexpr (q == 2) y = dpp1<0x4E>(y);
    else if constexpr (q == 3) y = dpp1<0x1B>(y);
    return dpp1<0x141>(y);                      // ^7 (row_half_mirror)
  } else if constexpr (VL >= 12) {              // VL = q ^ 12, 12 = 3^15
    constexpr int q = (VL & 3) ^ 3;
    int y = x;
    if constexpr (q == 1) y = dpp1<0xB1>(y);
    else if constexpr (q == 2) y = dpp1<0x4E>(y);
    else if constexpr (q == 3) y = dpp1<0x1B>(y);
    return dpp1<0x140>(y);                      // ^15 (row_mirror)
  } else {                                      // 8..11: VL = a ^ 7 ^ 15
    constexpr int a = VL & 3;
    int y = x;
    if constexpr (a == 1) y = dpp1<0xB1>(y);
    else if constexpr (a == 2) y = dpp1<0x4E>(y);
    else if constexpr (a == 3) y = dpp1<0x1B>(y);
    y = dpp1<0x141>(y);
    return dpp1<0x140>(y);
  }
}
template<int VL>
__device__ __forceinline__ float lx(float x) {  // general xor-VL lane exchange
  if constexpr (VL == 0) return x;
  else if constexpr (VL & 32) {
    int addr = ((int)threadIdx.x ^ VL) << 2;
    return __int_as_float(__builtin_amdgcn_ds_bpermute(addr, __float_as_int(x)));
  } else if constexpr (VL & 16) {
    return __int_as_float(__builtin_amdgcn_ds_swizzle(__float_as_int(x), (VL << 10) | 0x1F));
  } else {
    return __int_as_float(lxi<VL>(__float_as_int(x)));
  }
}
__device__ __forceinline__ float xsum(float x) {  // sum over all 64 lanes
  x += lx<1>(x); x += lx<2>(x); x += lx<4>(x);
  x += lx<8>(x); x += lx<16>(x); x += lx<32>(x);
  return x;
}
__device__ __forceinline__ float rdl(float x, int l) {
  return __int_as_float(__builtin_amdgcn_readlane(__float_as_int(x), l));
}

// ---------------- gate: fused constant SU(2) ----------------
template<int V, int M, int G>
__device__ __forceinline__ void gate_u(v2* amp, const float4* uu, int lane) {
  constexpr int VL = lanePart(V), VR = regPart(V);
  constexpr int LM = lanePart(M), RM = regPart(M);
  v2 p[16];
#pragma unroll
  for (int r = 0; r < 16; ++r) {
    v2 a0 = amp[r ^ VR];
    p[r].x = lx<VL>(a0.x);
    p[r].y = lx<VL>(a0.y);
  }
  float4 U0 = uu[2 * G], U1 = uu[2 * G + 1];
  const bool plw = (__popc(lane & LM) & 1) != 0;
  v2 u00 = {U0.x, U0.y}, u01 = {U0.z, U0.w}, u10 = {U1.x, U1.y}, u11 = {U1.z, U1.w};
  v2 A0 = plw ? u11 : u00, B0 = plw ? u10 : u01;
  v2 A1 = plw ? u00 : u11, B1 = plw ? u01 : u10;
  v2 A0n = {-A0.y, A0.y}, B0n = {-B0.y, B0.y};
  v2 A1n = {-A1.y, A1.y}, B1n = {-B1.y, B1.y};
#pragma unroll
  for (int r = 0; r < 16; ++r) {
    constexpr bool prM = false; (void)prM;
    const bool pr = (__popc(r & RM) & 1) != 0;
    v2 A = pr ? A1 : A0, An = pr ? A1n : A0n;
    v2 B = pr ? B1 : B0, Bn = pr ? B1n : B0n;
    v2 o = amp[r], q = p[r];
    v2 res = A.x * o;
    res += An * __builtin_shufflevector(o, o, 1, 0);
    res += B.x * q;
    res += Bn * __builtin_shufflevector(q, q, 1, 0);
    amp[r] = res;
  }
}

// ---------------- <X_w>: sum_s Re(conj(a_{s^v}) a_s), per-lane partial -------
template<int V>
__device__ __forceinline__ float xdot(const v2* amp) {
  constexpr int VL = lanePart(V), VR = regPart(V);
  v2 acc = {0.f, 0.f};
#pragma unroll
  for (int r = 0; r < 16; ++r) {
    v2 a0 = amp[r ^ VR];
    v2 p; p.x = lx<VL>(a0.x); p.y = lx<VL>(a0.y);
    acc += amp[r] * p;
  }
  return acc.x + acc.y;
}

// ---------- precompute kernel: h-independent per-step tables ----------
// rec layout (52 floats): [w*4+0]=cos(a*dt) [1]=sin(a*dt) [2]=C_w [3]=D_w*a_w, [40+w]=dt_angle
__global__ __launch_bounds__(256) void qmamba_pre(
    const float* __restrict__ angles, const float* __restrict__ Wx,
    const float* __restrict__ Wdt, const float* __restrict__ bdt,
    const float* __restrict__ Dg, float* __restrict__ tbl)
{
  int idx = blockIdx.x * 256 + threadIdx.x;
  if (idx >= NB * SEQ) return;
  const float* ar = angles + (size_t)idx * NQ;
  float a[NQ];
#pragma unroll
  for (int n = 0; n < NQ; ++n) a[n] = ar[n];
  float dtr[5];
#pragma unroll
  for (int r = 0; r < 5; ++r) {
    float acc = 0.f;
#pragma unroll
    for (int n = 0; n < NQ; ++n) acc += a[n] * Wx[r * NQ + n];
    dtr[r] = acc;
  }
  float* rec = tbl + (size_t)idx * RECF;
#pragma unroll
  for (int w = 0; w < NQ; ++w) {
    float lin = bdt[w];
#pragma unroll
    for (int r = 0; r < 5; ++r) lin += dtr[r] * Wdt[w * 5 + r];
    float sp = lin > 0.f ? lin + log1pf(__expf(-lin)) : log1pf(__expf(lin));
    float th = tanhf(sp) * PIF;                  // dt_angles
    float fa = a[w] * th;                        // FULL final-RY angle
    float Cv = 0.f;
#pragma unroll
    for (int n = 0; n < NQ; ++n) Cv += a[n] * Wx[(15 + w) * NQ + n];
    rec[w * 4 + 0] = __cosf(fa);
    rec[w * 4 + 1] = __sinf(fa);
    rec[w * 4 + 2] = Cv;
    rec[w * 4 + 3] = Dg[w] * a[w];
    rec[40 + w]    = th;
  }
}

// ---------------- main scan kernel ----------------
__global__ __launch_bounds__(NTHR, 1) void qmamba_main(
    const float* __restrict__ angles, const float* __restrict__ Wx,
    const float* __restrict__ Wdt, const float* __restrict__ bdt,
    const float* __restrict__ pc, const float* __restrict__ cp,
    const float* __restrict__ Dg, const float* __restrict__ tbl,
    float* __restrict__ out)
{
  __shared__ float4 uuL[40];                 // fused U per gate: {u00,u01},{u10,u11}
  __shared__ float  zbuf[SEQ * NQ];          // 20 KB output staging

  const int lane = threadIdx.x;
  const int b    = blockIdx.x;

  if (lane < 20) {
    int k = lane * 3;
    float al = 0.5f * cp[k], be = 0.5f * cp[k + 1], ga = 0.5f * cp[k + 2];
    float ca = __cosf(al), sa = __sinf(al);
    float cb = __cosf(be), sb = __sinf(be);
    float cg = __cosf(ga), sg = __sinf(ga);
    float2 M00 = make_float2(cb * ca,  sb * sa);
    float2 M01 = make_float2(-sb * ca, -cb * sa);
    float2 M10 = make_float2(sb * ca,  -cb * sa);
    float2 M11 = make_float2(cb * ca,  -sb * sa);
    float2 e0 = make_float2(cg, -sg), e1 = make_float2(cg, sg);
    auto cm = [](float2 a, float2 c) {
      return make_float2(a.x * c.x - a.y * c.y, a.x * c.y + a.y * c.x);
    };
    float2 u00 = cm(M00, e0), u01 = cm(M01, e0), u10 = cm(M10, e1), u11 = cm(M11, e1);
    uuL[2 * lane]     = make_float4(u00.x, u00.y, u01.x, u01.y);
    uuL[2 * lane + 1] = make_float4(u10.x, u10.y, u11.x, u11.y);
  }

  float pch[4];
#pragma unroll
  for (int d = 0; d < 4; ++d) pch[d] = 0.5f * pc[d] * PIF;
  const int wme = lane < NQ ? lane : 9;
  const float Dv = Dg[wme];                  // fallback only

  // hoisted lane-parity bits for the 40 fused-RZ masks
  unsigned PW0 = 0, PW1 = 0;
#pragma unroll
  for (int k = 0; k < 40; ++k) {
    const int lm = lanePart(CT.mz[k / 10][k % 10]);
    unsigned flip = (__popc(lane & lm) & 1) ^ 1;    // +th iff lane-parity odd
    if (k < 32) PW0 |= flip << k; else PW1 |= flip << (k - 32);
  }

  float hcw[NQ], hsw[NQ];
#pragma unroll
  for (int w = 0; w < NQ; ++w) { hcw[w] = 1.f; hsw[w] = 0.f; }

  const bool useT = (tbl != nullptr);
  float4 pfc = make_float4(0.f, 0.f, 0.f, 0.f);
  if (useT && lane < 13)
    pfc = ((const float4*)(tbl + (size_t)(b * SEQ) * RECF))[lane];

  v2 amp[16];

#pragma unroll 1
  for (int t = 0; t < SEQ; ++t) {
    float thw[NQ], cfv[NQ], sfv[NQ], Cp, Dap;

    if (useT) {
#pragma unroll
      for (int w = 0; w < NQ; ++w) {
        cfv[w] = rdl(pfc.x, w);
        sfv[w] = rdl(pfc.y, w);
        float c = ((w & 3) == 0) ? pfc.x : ((w & 3) == 1) ? pfc.y : ((w & 3) == 2) ? pfc.z : pfc.w;
        thw[w] = rdl(c, 10 + (w >> 2));
      }
      Cp = pfc.z; Dap = pfc.w;               // valid for lane<10
      // prefetch next step's record (hidden across the whole step)
      int nidx = b * SEQ + t + 1;
      if (nidx > NB * SEQ - 1) nidx = NB * SEQ - 1;
      if (lane < 13) pfc = ((const float4*)(tbl + (size_t)nidx * RECF))[lane];
    } else {
      const float* arow = angles + (size_t)(b * SEQ + t) * NQ;
      float a[NQ];
#pragma unroll
      for (int n = 0; n < NQ; ++n) a[n] = arow[n];
      float dtr[5];
#pragma unroll
      for (int r = 0; r < 5; ++r) {
        float acc = 0.f;
#pragma unroll
        for (int n = 0; n < NQ; ++n) acc += a[n] * Wx[r * NQ + n];
        dtr[r] = acc;
      }
#pragma unroll
      for (int w = 0; w < NQ; ++w) {
        float lin = bdt[w];
#pragma unroll
        for (int r = 0; r < 5; ++r) lin += dtr[r] * Wdt[w * 5 + r];
        float sp = lin > 0.f ? lin + log1pf(__expf(-lin)) : log1pf(__expf(lin));
        float th = tanhf(sp) * PIF;
        thw[w] = th;
        float fa = a[w] * th;
        cfv[w] = __cosf(fa);
        sfv[w] = __sinf(fa);
      }
      float Cacc = 0.f;
#pragma unroll
      for (int n = 0; n < NQ; ++n) Cacc += a[n] * Wx[(15 + wme) * NQ + n];
      Cp = Cacc; Dap = Dv * a[wme];
    }

    // ---- Phase A: real product state from RY(h)|0>
    // lane slots -> wires: L0=w9 L1=w4 L2=w8 L3=w2 L4=w6 L5=w0; regs: r0=w7 r1=w5 r2=w3 r3=w1
    float F;
    F  = (lane & 1)  ? hsw[9] : hcw[9];
    F *= (lane & 2)  ? hsw[4] : hcw[4];
    F *= (lane & 4)  ? hsw[8] : hcw[8];
    F *= (lane & 8)  ? hsw[2] : hcw[2];
    F *= (lane & 16) ? hsw[6] : hcw[6];
    F *= (lane & 32) ? hsw[0] : hcw[0];
    float G[16];
    {
      float g01[4], g23[4];
      g01[0] = hcw[7] * hcw[5]; g01[1] = hsw[7] * hcw[5];
      g01[2] = hcw[7] * hsw[5]; g01[3] = hsw[7] * hsw[5];
      g23[0] = hcw[3] * hcw[1]; g23[1] = hsw[3] * hcw[1];
      g23[2] = hcw[3] * hsw[1]; g23[3] = hsw[3] * hsw[1];
#pragma unroll
      for (int r = 0; r < 16; ++r) G[r] = F * g01[r & 3] * g23[(r >> 2) & 3];
    }

    // ---- Phase B: fused 40-RZ phase (bucket by reg-class + 16-pt Walsh)
    float S[16];
#pragma unroll
    for (int g = 0; g < 16; ++g) S[g] = 0.f;
#pragma unroll
    for (int k = 0; k < 40; ++k) {
      const int m  = CT.mz[k / 10][k % 10];
      const int gr = regPart(m);
      float v = pch[k / 10] * thw[k % 10];
      unsigned fl = ((k < 32 ? (PW0 >> k) : (PW1 >> (k - 32))) & 1u) << 31;
      S[gr] += __int_as_float(__float_as_int(v) ^ fl);
    }
#pragma unroll
    for (int bb = 1; bb < 16; bb <<= 1) {
#pragma unroll
      for (int g = 0; g < 16; ++g)
        if (!(g & bb)) { float x = S[g], y = S[g | bb]; S[g] = x + y; S[g | bb] = x - y; }
    }
#pragma unroll
    for (int r = 0; r < 16; ++r) {
      float sn, cs;
      __sincosf(S[r], &sn, &cs);
      amp[r].x = G[r] * cs;
      amp[r].y = G[r] * sn;
    }

    // ---- Phase C: 20 fused variational SU(2) gates (classified at compile time)
#define GU(L, I) gate_u<CT.vu[L][I], CT.mu[L][I], (L) * NQ + (I)>(amp, uuL, lane);
    GU(0, 0) GU(0, 1) GU(0, 2) GU(0, 3) GU(0, 4)
    GU(0, 5) GU(0, 6) GU(0, 7) GU(0, 8) GU(0, 9)
    GU(1, 0) GU(1, 1) GU(1, 2) GU(1, 3) GU(1, 4)
    GU(1, 5) GU(1, 6) GU(1, 7) GU(1, 8) GU(1, 9)
#undef GU

    // ---- measurement with fused final-RY: z_w = cos*<Z_w> - sin*<X_w>
    float T[16];
#pragma unroll
    for (int r = 0; r < 16; ++r) T[r] = amp[r].x * amp[r].x + amp[r].y * amp[r].y;
#pragma unroll
    for (int bb = 1; bb < 16; bb <<= 1) {
#pragma unroll
      for (int g = 0; g < 16; ++g)
        if (!(g & bb)) { float x = T[g], y = T[g | bb]; T[g] = x + y; T[g | bb] = x - y; }
    }
    float zt[NQ];
#define MEAS(W) {                                                   \
      constexpr int zmv = CT.zm[W];                                 \
      float zp = T[regPart(zmv)];                                   \
      if (__popc(lane & lanePart(zmv)) & 1) zp = -zp;               \
      float xp = xdot<CT.vf[W]>(amp);                               \
      zt[W] = xsum(cfv[W] * zp - sfv[W] * xp);                      \
    }
    MEAS(0) MEAS(1) MEAS(2) MEAS(3) MEAS(4)
    MEAS(5) MEAS(6) MEAS(7) MEAS(8) MEAS(9)
#undef MEAS

    // h for next step (redundant per-lane, no communication)
#pragma unroll
    for (int w = 0; w < NQ; ++w) {
      float sn, cs;
      __sincosf(0.5f * zt[w], &sn, &cs);
      hcw[w] = cs; hsw[w] = sn;
    }

    // output -> LDS staging (no global ops in loop)
    float zsel = zt[0];
#pragma unroll
    for (int w = 1; w < NQ; ++w) zsel = (lane == w) ? zt[w] : zsel;
    if (lane < NQ) zbuf[t * NQ + lane] = Cp * zsel + Dap;
  }

  // ---- epilogue: bulk-store the staged outputs (coalesced float4)
#pragma unroll
  for (int j = 0; j < 20; ++j) {
    int i = j * 256 + lane * 4;
    float4 v = *(const float4*)&zbuf[i];
    *(float4*)&out[(size_t)b * (SEQ * NQ) + i] = v;
  }
}

extern "C" void kernel_launch(void* const* d_in, const int* in_sizes, int n_in,
                              void* d_out, int out_size, void* d_ws, size_t ws_size,
                              hipStream_t stream) {
  (void)in_sizes; (void)n_in; (void)out_size;
  const float* angles = (const float*)d_in[0];
  const float* Wx     = (const float*)d_in[1];
  const float* Wdt    = (const float*)d_in[2];
  const float* bdt    = (const float*)d_in[3];
  const float* pc     = (const float*)d_in[4];
  const float* cp     = (const float*)d_in[5];
  const float* Dg     = (const float*)d_in[6];
  float* out = (float*)d_out;

  float* tbl = nullptr;
  const size_t need = (size_t)NB * SEQ * RECF * sizeof(float);
  if (ws_size >= need) {
    tbl = (float*)d_ws;
    hipLaunchKernelGGL(qmamba_pre, dim3((NB * SEQ + 255) / 256), dim3(256), 0, stream,
                       angles, Wx, Wdt, bdt, Dg, tbl);
  }
  hipLaunchKernelGGL(qmamba_main, dim3(NB), dim3(NTHR), 0, stream,
                     angles, Wx, Wdt, bdt, pc, cp, Dg, tbl, out);
}